// Round 11
// baseline (1499.220 us; speedup 1.0000x reference)
//
#include <hip/hip_runtime.h>

typedef unsigned int u32;
typedef _Float16 f16;
typedef __attribute__((ext_vector_type(8))) _Float16 half8;
typedef __attribute__((ext_vector_type(2))) _Float16 half2_t;
typedef __attribute__((ext_vector_type(4))) float f32x4;

#define D_IN 128
#define D_HID 128
#define D_OUT 16
#define RPB 128        // rows per bucket (lr fits in 7 bits; c < 2^20)
#define MAXBUCK 1024   // supports N <= 131072
#define CHUNK 16384    // edges per hist/scatter block (256 thr x 64)
#define PGRAN 16       // pad each row's edge run to a multiple of 16
#define SLACK 2048     // per-bucket capacity bonus; mult of 16, >= 128*15+15

// ---------------- preprocessing ----------------

// flag: 1 if edge_index is int32 layout, 0 if int64 (odd words all zero).
__global__ __launch_bounds__(256) void detect_k(const int* __restrict__ ei,
                                                u32* __restrict__ flag, int n) {
    int i = blockIdx.x * 256 + threadIdx.x;
    if (i < n && (i & 1) && ei[i] != 0) atomicOr(flag, 1u);
}

__device__ inline int load_row(const int* ei, u32 f, int e, int E) {
    return f ? ei[e] : ei[2 * e];
}
__device__ inline int load_col(const int* ei, u32 f, int e, int E) {
    return f ? ei[E + e] : ei[2 * E + 2 * e];
}
__device__ inline int clampi(int v, int n) {
    v = v < 0 ? 0 : v;
    return v >= n ? n - 1 : v;
}
__device__ inline u32 al16(u32 v) { return (v + 15u) & ~15u; }

// Pass 1: per-block histogram over row-buckets (bucket-major Hmat, plain
// stores — no global atomics at all).
__global__ __launch_bounds__(256) void hist_k(const int* __restrict__ ei,
                                              const u32* __restrict__ flag,
                                              u32* __restrict__ Hmat,
                                              int E, int N, int NBK, int NB) {
    __shared__ u32 lh[MAXBUCK];
    int tid = threadIdx.x;
    for (int i = tid; i < NBK; i += 256) lh[i] = 0;
    __syncthreads();
    u32 f = *flag;
    int base = blockIdx.x * CHUNK;
    int lim = base + CHUNK < E ? base + CHUNK : E;
    for (int e = base + tid; e < lim; e += 256) {
        int r = clampi(load_row(ei, f, e, E), N);
        atomicAdd(&lh[(u32)r >> 7], 1u);
    }
    __syncthreads();
    for (int i = tid; i < NBK; i += 256)
        Hmat[(size_t)i * NB + blockIdx.x] = lh[i];
}

__global__ __launch_bounds__(256) void scan1(const u32* __restrict__ cnt,
                                             u32* __restrict__ excl,
                                             u32* __restrict__ partial, int n) {
    __shared__ u32 sm[256];
    int tid = threadIdx.x;
    int i = blockIdx.x * 256 + tid;
    u32 v = (i < n) ? cnt[i] : 0u;
    sm[tid] = v;
    __syncthreads();
    for (int off = 1; off < 256; off <<= 1) {
        u32 t = (tid >= off) ? sm[tid - off] : 0u;
        __syncthreads();
        sm[tid] += t;
        __syncthreads();
    }
    if (i < n) excl[i] = sm[tid] - v;
    if (tid == 255) partial[blockIdx.x] = sm[255];
}

__global__ __launch_bounds__(512) void scan2(u32* __restrict__ partial, int nb) {
    __shared__ u32 sm[512];
    int tid = threadIdx.x;
    u32 v = (tid < nb) ? partial[tid] : 0u;
    sm[tid] = v;
    __syncthreads();
    for (int off = 1; off < 512; off <<= 1) {
        u32 t = (tid >= off) ? sm[tid - off] : 0u;
        __syncthreads();
        sm[tid] += t;
        __syncthreads();
    }
    if (tid < nb) partial[tid] = sm[tid] - v;
}

__global__ __launch_bounds__(256) void scan3(u32* __restrict__ excl,
                                             const u32* __restrict__ partial,
                                             int n, int E) {
    int i = blockIdx.x * 256 + threadIdx.x;
    if (i < n) excl[i] += partial[blockIdx.x];
    if (i == 0) excl[n] = (u32)E;
}

// Pass 2: re-read edges; block-exact frontiers per bucket (from scanned Hmat),
// only LDS atomics. Record = (r&127)<<20 | c (u32, c < 2^20).
__global__ __launch_bounds__(256) void scatter_bd(const int* __restrict__ ei,
                                                  const u32* __restrict__ flag,
                                                  const u32* __restrict__ Hbase,
                                                  u32* __restrict__ bdata,
                                                  int E, int N, int NBK, int NB) {
    __shared__ u32 lbase[MAXBUCK];
    int tid = threadIdx.x;
    for (int i = tid; i < NBK; i += 256)
        lbase[i] = Hbase[(size_t)i * NB + blockIdx.x];
    __syncthreads();
    u32 f = *flag;
    int base = blockIdx.x * CHUNK;
    int lim = base + CHUNK < E ? base + CHUNK : E;
    for (int e = base + tid; e < lim; e += 256) {
        int r = clampi(load_row(ei, f, e, E), N);
        int c = clampi(load_col(ei, f, e, E), N);
        u32 pos = atomicAdd(&lbase[(u32)r >> 7], 1u);
        if (pos < (u32)E) bdata[pos] = ((u32)(r & (RPB - 1)) << 20) | (u32)c;
    }
}

// Pass 3: one block per bucket. PADDED CSR with 16-ALIGNED region boundaries:
// pbase(b) = align16(s) + b*SLACK, so every row_start (pexcl/pdeg are mults of
// 16) and every region end is 16-aligned -> ALL per-row ranges (incl. the
// slack-extended last row of a bucket) have length % 16 == 0, and the agg
// batch loop can never overrun into the next bucket's real data. Pad/slack
// entries -> sentinel col N (zero h-row). Capacity: align16(t)-align16(s)
// + SLACK >= (t-s)+2033 >= ptot (max (t-s)+1920). [R10 bug: unaligned pbase
// made slack length non-mult-16 -> batch loop read next bucket's real cols.]
__global__ __launch_bounds__(256) void finalize_k(const u32* __restrict__ bdata,
                                                  const u32* __restrict__ Hbase,
                                                  u32* __restrict__ row_start,
                                                  float* __restrict__ dinv,
                                                  u32* __restrict__ ecol,
                                                  int N, int E, int NB) {
    __shared__ u32 smc[RPB];
    __shared__ u32 cur[RPB];
    int b = blockIdx.x;
    int tid = threadIdx.x;
    u32 s = Hbase[(size_t)b * NB];
    u32 t = Hbase[(size_t)(b + 1) * NB];  // last bucket hits sentinel = E
    u32 pbase = al16(s) + (u32)b * SLACK;
    u32 pnext = al16(t) + (u32)(b + 1) * SLACK;
    if (tid < RPB) smc[tid] = 0;
    __syncthreads();
    for (u32 i = s + tid; i < t; i += 256)
        atomicAdd(&smc[bdata[i] >> 20], 1u);
    __syncthreads();
    u32 deg = (tid < RPB) ? smc[tid] : 0;
    u32 pdeg = (deg + PGRAN - 1) & ~(u32)(PGRAN - 1);
    if (tid < RPB) smc[tid] = pdeg;
    __syncthreads();
    for (int off = 1; off < RPB; off <<= 1) {
        u32 tv = (tid < RPB && tid >= off) ? smc[tid - off] : 0u;
        __syncthreads();
        if (tid < RPB) smc[tid] += tv;
        __syncthreads();
    }
    u32 ptot = smc[RPB - 1];
    u32 pexcl = (tid < RPB) ? (smc[tid] - pdeg) : 0;
    if (tid < RPB) {
        int r = b * RPB + tid;
        if (r < N) {
            row_start[r] = pbase + pexcl;
            dinv[r] = rsqrtf((float)(deg + 1u));  // +1 self loop
            if (r == N - 1) row_start[N] = pbase + pexcl + pdeg;
        }
        cur[tid] = pbase + pexcl;
    }
    __syncthreads();
    for (u32 i = s + tid; i < t; i += 256) {
        u32 rec = bdata[i];
        u32 pos = atomicAdd(&cur[rec >> 20], 1u);
        ecol[pos] = rec & 0xFFFFFu;
    }
    __syncthreads();
    if (tid < RPB) {  // per-row pad tail -> sentinel
        u32 st = pbase + pexcl;
        for (u32 k = deg; k < pdeg; k++) ecol[st + k] = (u32)N;
    }
    // bucket slack [pbase+ptot, pnext) -> sentinel (length % 16 == 0)
    for (u32 i = pbase + ptot + tid; i < pnext; i += 256) ecol[i] = (u32)N;
}

// Split fp32 W into hi/lo f16 MFMA B-fragments. Blocks 0-7 -> W1, 8-15 -> W2,
// 16 -> W3, 17 -> zero the sentinel rows h[N], h3[N].
__global__ __launch_bounds__(256) void reformat_all(const float* __restrict__ W1,
                                                    const float* __restrict__ W2,
                                                    const float* __restrict__ W3,
                                                    f16* __restrict__ W1h, f16* __restrict__ W1l,
                                                    f16* __restrict__ W2h, f16* __restrict__ W2l,
                                                    f16* __restrict__ W3h, f16* __restrict__ W3l,
                                                    f16* __restrict__ hzero,
                                                    f16* __restrict__ h3zero) {
    if (blockIdx.x == 17) {
        int tix = threadIdx.x;
        if (tix < 128) hzero[tix] = (f16)0;
        else if (tix < 144) h3zero[tix - 128] = (f16)0;
        return;
    }
    const float* W;
    f16 *Wh, *Wl;
    int ntiles, bidx;
    if (blockIdx.x < 8) { W = W1; Wh = W1h; Wl = W1l; ntiles = 8; bidx = blockIdx.x; }
    else if (blockIdx.x < 16) { W = W2; Wh = W2h; Wl = W2l; ntiles = 8; bidx = blockIdx.x - 8; }
    else { W = W3; Wh = W3h; Wl = W3l; ntiles = 1; bidx = 0; }
    int idx = bidx * 256 + threadIdx.x;
    int total = 4 * ntiles * 64;
    if (idx >= total) return;
    int lane = idx & 63;
    int st = idx >> 6;
    int t = st % ntiles;
    int s = st / ntiles;
    int Nc = ntiles * 16;
    int n = t * 16 + (lane & 15);
    int kb = lane >> 4;
    half8 vh, vl;
#pragma unroll
    for (int j = 0; j < 8; j++) {
        float w = W[(size_t)(s * 32 + kb * 8 + j) * Nc + n];
        f16 hi = (f16)w;
        f16 lo = (f16)(w - (float)hi);
        vh[j] = hi;
        vl[j] = lo;
    }
    *(half8*)(Wh + (size_t)idx * 8) = vh;
    *(half8*)(Wl + (size_t)idx * 8) = vl;
}

// ---------------- GEMMs (f16 MFMA 16x16x32, fp32-accurate via splits) --------

// Layer 1: A fp32 [M x 128]; 3 MFMAs; epilogue scales row rr by dinv[rr]
// so the stored table is h' = (x@W1)*dinv  (norm folded into storage).
__global__ __launch_bounds__(256) void gemm128_l1(const float* __restrict__ A,
                                                  const f16* __restrict__ Wh,
                                                  const f16* __restrict__ Wl,
                                                  const float* __restrict__ dinv,
                                                  f16* __restrict__ H, int M) {
    int wave = threadIdx.x >> 6, lane = threadIdx.x & 63;
    int mbase = blockIdx.x * 64 + wave * 16;
    int mload = mbase + (lane & 15);
    if (mload >= M) mload = M - 1;
    int kq = lane >> 4;
    f32x4 acc[8];
#pragma unroll
    for (int t = 0; t < 8; t++) acc[t] = (f32x4){0.f, 0.f, 0.f, 0.f};
#pragma unroll
    for (int s = 0; s < 4; s++) {
        const float* ap = A + (size_t)mload * 128 + s * 32 + kq * 8;
        half8 ah, al;
#pragma unroll
        for (int j = 0; j < 8; j++) {
            float v = ap[j];
            f16 hi = (f16)v;
            ah[j] = hi;
            al[j] = (f16)(v - (float)hi);
        }
#pragma unroll
        for (int t = 0; t < 8; t++) {
            half8 bh = *(const half8*)(Wh + (size_t)((s * 8 + t) * 64 + lane) * 8);
            half8 bl = *(const half8*)(Wl + (size_t)((s * 8 + t) * 64 + lane) * 8);
            acc[t] = __builtin_amdgcn_mfma_f32_16x16x32_f16(ah, bh, acc[t], 0, 0, 0);
            acc[t] = __builtin_amdgcn_mfma_f32_16x16x32_f16(ah, bl, acc[t], 0, 0, 0);
            acc[t] = __builtin_amdgcn_mfma_f32_16x16x32_f16(al, bh, acc[t], 0, 0, 0);
        }
    }
    int coln = lane & 15;
    int rbase = mbase + ((lane >> 4) << 2);
    float dsc[4];
#pragma unroll
    for (int i = 0; i < 4; i++) {
        int rr = rbase + i;
        dsc[i] = dinv[rr < M ? rr : M - 1];
    }
#pragma unroll
    for (int t = 0; t < 8; t++) {
#pragma unroll
        for (int i = 0; i < 4; i++) {
            int rr = rbase + i;
            if (rr < M) H[(size_t)rr * 128 + t * 16 + coln] = (f16)(acc[t][i] * dsc[i]);
        }
    }
}

// Layer 2: A f16 (pre-scaled act') [M x 128]; 2 MFMAs; output inherits the
// dinv row-scale automatically ((act*dinv)@W = (act@W)*dinv).
__global__ __launch_bounds__(256) void gemm128_l2(const f16* __restrict__ A,
                                                  const f16* __restrict__ Wh,
                                                  const f16* __restrict__ Wl,
                                                  f16* __restrict__ H, int M) {
    int wave = threadIdx.x >> 6, lane = threadIdx.x & 63;
    int mbase = blockIdx.x * 64 + wave * 16;
    int mload = mbase + (lane & 15);
    if (mload >= M) mload = M - 1;
    int kq = lane >> 4;
    f32x4 acc[8];
#pragma unroll
    for (int t = 0; t < 8; t++) acc[t] = (f32x4){0.f, 0.f, 0.f, 0.f};
#pragma unroll
    for (int s = 0; s < 4; s++) {
        half8 a = *(const half8*)(A + (size_t)mload * 128 + s * 32 + kq * 8);
#pragma unroll
        for (int t = 0; t < 8; t++) {
            half8 bh = *(const half8*)(Wh + (size_t)((s * 8 + t) * 64 + lane) * 8);
            half8 bl = *(const half8*)(Wl + (size_t)((s * 8 + t) * 64 + lane) * 8);
            acc[t] = __builtin_amdgcn_mfma_f32_16x16x32_f16(a, bh, acc[t], 0, 0, 0);
            acc[t] = __builtin_amdgcn_mfma_f32_16x16x32_f16(a, bl, acc[t], 0, 0, 0);
        }
    }
    int coln = lane & 15;
    int rbase = mbase + ((lane >> 4) << 2);
#pragma unroll
    for (int t = 0; t < 8; t++) {
#pragma unroll
        for (int i = 0; i < 4; i++) {
            int rr = rbase + i;
            if (rr < M) H[(size_t)rr * 128 + t * 16 + coln] = (f16)acc[t][i];
        }
    }
}

// Layer 3: A f16 (pre-scaled) [M x 128] -> H3' f16 [M x 16].
__global__ __launch_bounds__(256) void gemm16(const f16* __restrict__ A,
                                              const f16* __restrict__ Wh,
                                              const f16* __restrict__ Wl,
                                              f16* __restrict__ H, int M) {
    int wave = threadIdx.x >> 6, lane = threadIdx.x & 63;
    int mbase = blockIdx.x * 64 + wave * 16;
    int mload = mbase + (lane & 15);
    if (mload >= M) mload = M - 1;
    int kq = lane >> 4;
    f32x4 acc = (f32x4){0.f, 0.f, 0.f, 0.f};
#pragma unroll
    for (int s = 0; s < 4; s++) {
        half8 a = *(const half8*)(A + (size_t)mload * 128 + s * 32 + kq * 8);
        half8 bh = *(const half8*)(Wh + (size_t)(s * 64 + lane) * 8);
        half8 bl = *(const half8*)(Wl + (size_t)(s * 64 + lane) * 8);
        acc = __builtin_amdgcn_mfma_f32_16x16x32_f16(a, bh, acc, 0, 0, 0);
        acc = __builtin_amdgcn_mfma_f32_16x16x32_f16(a, bl, acc, 0, 0, 0);
    }
    int coln = lane & 15;
    int rbase = mbase + ((lane >> 4) << 2);
#pragma unroll
    for (int i = 0; i < 4; i++) {
        int rr = rbase + i;
        if (rr < M) H[(size_t)rr * 16 + coln] = (f16)acc[i];
    }
}

// ---------------- aggregation ----------------
// One wave per row; lane handles features 2*lane, 2*lane+1 (half2, 4B/lane ->
// one coalesced 256B gather per edge). Padded CSR: every row range length is
// a multiple of 16 (pad entries -> sentinel zero-row) so the loop is a single
// full-width 16-batch with NO tail round-trips. f32 accumulation (R8 numerics).
__global__ __launch_bounds__(256) void agg128(const f16* __restrict__ h,
                                              const u32* __restrict__ ecol,
                                              const u32* __restrict__ row_start,
                                              const float* __restrict__ dinv,
                                              const float* __restrict__ bias,
                                              f16* __restrict__ out, int M) {
    int wave = threadIdx.x >> 6, lane = threadIdx.x & 63;
    int r = blockIdx.x * 4 + wave;
    if (r >= M) return;
    u32 beg = row_start[r], end = row_start[r + 1];
    const half2_t* hp = (const half2_t*)h;
    float ax0 = 0, ay0 = 0, ax1 = 0, ay1 = 0, ax2 = 0, ay2 = 0, ax3 = 0, ay3 = 0;
    for (u32 e = beg; e < end; e += 16) {
        u32 c[16];
#pragma unroll
        for (int j = 0; j < 16; j++) c[j] = ecol[e + j];
        half2_t v[16];
#pragma unroll
        for (int j = 0; j < 16; j++) v[j] = hp[(size_t)c[j] * 64 + lane];
#pragma unroll
        for (int j = 0; j < 16; j += 4) {
            ax0 += (float)v[j][0];     ay0 += (float)v[j][1];
            ax1 += (float)v[j + 1][0]; ay1 += (float)v[j + 1][1];
            ax2 += (float)v[j + 2][0]; ay2 += (float)v[j + 2][1];
            ax3 += (float)v[j + 3][0]; ay3 += (float)v[j + 3][1];
        }
    }
    half2_t vs = hp[(size_t)r * 64 + lane];
    float dr = dinv[r];
    float2 bb = ((const float2*)bias)[lane];
    float ax = (((ax0 + ax1) + (ax2 + ax3)) + (float)vs[0]) * dr + bb.x;
    float ay = (((ay0 + ay1) + (ay2 + ay3)) + (float)vs[1]) * dr + bb.y;
    ax = fmaxf(ax, 0.f) * dr;  // pre-scale for next layer's gather
    ay = fmaxf(ay, 0.f) * dr;
    half2_t o;
    o[0] = (f16)ax;
    o[1] = (f16)ay;
    ((half2_t*)out)[(size_t)r * 64 + lane] = o;
}

// 16 lanes per row; h3' pre-scaled; padded CSR -> pure 8-batches, no tail.
__global__ __launch_bounds__(256) void agg16_lsm(const f16* __restrict__ h3,
                                                 const u32* __restrict__ ecol,
                                                 const u32* __restrict__ row_start,
                                                 const float* __restrict__ dinv,
                                                 const float* __restrict__ bias,
                                                 float* __restrict__ out, int M) {
    int g = threadIdx.x >> 4, l = threadIdx.x & 15;
    int r = blockIdx.x * 16 + g;
    if (r >= M) return;
    u32 beg = row_start[r], end = row_start[r + 1];
    float a0 = 0.f, a1 = 0.f, a2 = 0.f, a3 = 0.f;
    for (u32 e = beg; e < end; e += 8) {
        u32 c[8];
#pragma unroll
        for (int j = 0; j < 8; j++) c[j] = ecol[e + j];
        f16 v[8];
#pragma unroll
        for (int j = 0; j < 8; j++) v[j] = h3[(size_t)c[j] * 16 + l];
        a0 += (float)v[0] + (float)v[4];
        a1 += (float)v[1] + (float)v[5];
        a2 += (float)v[2] + (float)v[6];
        a3 += (float)v[3] + (float)v[7];
    }
    float dr = dinv[r];
    float acc = (((a0 + a1) + (a2 + a3)) + (float)h3[(size_t)r * 16 + l]) * dr +
                bias[l];
    float m = acc;
#pragma unroll
    for (int o = 8; o >= 1; o >>= 1) m = fmaxf(m, __shfl_xor(m, o, 16));
    float ex = expf(acc - m);
    float s = ex;
#pragma unroll
    for (int o = 8; o >= 1; o >>= 1) s += __shfl_xor(s, o, 16);
    out[(size_t)r * 16 + l] = acc - m - logf(s);
}

// ---------------- launch ----------------

extern "C" void kernel_launch(void* const* d_in, const int* in_sizes, int n_in,
                              void* d_out, int out_size, void* d_ws, size_t ws_size,
                              hipStream_t stream) {
    const float* x = (const float*)d_in[0];
    const int* ei = (const int*)d_in[1];
    const float* W1 = (const float*)d_in[2];
    const float* b1 = (const float*)d_in[3];
    const float* W2 = (const float*)d_in[4];
    const float* b2 = (const float*)d_in[5];
    const float* W3 = (const float*)d_in[6];
    const float* b3 = (const float*)d_in[7];
    int N = in_sizes[0] / D_IN;
    int E = in_sizes[1] / 2;

    int NBK = (N + RPB - 1) / RPB;     // 782 row-buckets (<= MAXBUCK)
    int NB = (E + CHUNK - 1) / CHUNK;  // 98 hist/scatter blocks
    int L = NBK * NB;                  // 76636 Hmat entries
    size_t Epad = ((size_t)E + 16) + (size_t)NBK * SLACK + 256;

    char* p = (char*)d_ws;
    auto alloc = [&](size_t bytes) -> void* {
        void* q = (void*)p;
        p += (bytes + 255) & ~(size_t)255;
        return q;
    };
    u32* flag = (u32*)alloc(256);
    float* dinv = (float*)alloc((size_t)N * 4);
    u32* row_start = (u32*)alloc((size_t)(N + 1) * 4);
    u32* partial2 = (u32*)alloc(4096);
    u32* Hmat = (u32*)alloc((size_t)(L + 1) * 4);
    u32* ecol = (u32*)alloc(Epad * 4);
    u32* bdata = (u32*)alloc((size_t)E * 4);
    f16* wf1h = (f16*)alloc(16384 * 2);
    f16* wf1l = (f16*)alloc(16384 * 2);
    f16* wf2h = (f16*)alloc(16384 * 2);
    f16* wf2l = (f16*)alloc(16384 * 2);
    f16* wf3h = (f16*)alloc(2048 * 2);
    f16* wf3l = (f16*)alloc(2048 * 2);
    f16* h = (f16*)alloc((size_t)(N + 1) * 128 * 2);   // +1 sentinel zero row
    f16* act = (f16*)alloc((size_t)N * 128 * 2);
    f16* h3 = (f16*)alloc((size_t)(N + 1) * 16 * 2);   // +1 sentinel zero row
    (void)ws_size; (void)n_in; (void)out_size;

    hipMemsetAsync(flag, 0, 4, stream);

    int nb2 = (L + 255) / 256;  // 300 <= 512 for scan2

    detect_k<<<32, 256, 0, stream>>>(ei, flag, 8192);
    hist_k<<<NB, 256, 0, stream>>>(ei, flag, Hmat, E, N, NBK, NB);
    scan1<<<nb2, 256, 0, stream>>>(Hmat, Hmat, partial2, L);
    scan2<<<1, 512, 0, stream>>>(partial2, nb2);
    scan3<<<nb2, 256, 0, stream>>>(Hmat, partial2, L, E);  // sentinel Hmat[L]=E
    scatter_bd<<<NB, 256, 0, stream>>>(ei, flag, Hmat, bdata, E, N, NBK, NB);
    finalize_k<<<NBK, 256, 0, stream>>>(bdata, Hmat, row_start, dinv, ecol,
                                        N, E, NB);

    reformat_all<<<18, 256, 0, stream>>>(W1, W2, W3, wf1h, wf1l, wf2h, wf2l,
                                         wf3h, wf3l,
                                         h + (size_t)N * 128,
                                         h3 + (size_t)N * 16);

    int gb = (N + 63) / 64;
    int ab = (N + 3) / 4;
    gemm128_l1<<<gb, 256, 0, stream>>>(x, wf1h, wf1l, dinv, h, N);
    agg128<<<ab, 256, 0, stream>>>(h, ecol, row_start, dinv, b1, act, N);
    gemm128_l2<<<gb, 256, 0, stream>>>(act, wf2h, wf2l, h, N);
    agg128<<<ab, 256, 0, stream>>>(h, ecol, row_start, dinv, b2, act, N);
    gemm16<<<gb, 256, 0, stream>>>(act, wf3h, wf3l, h3, N);
    agg16_lsm<<<(N + 15) / 16, 256, 0, stream>>>(h3, ecol, row_start, dinv, b3,
                                                 (float*)d_out, N);
}

// Round 12
// 393.388 us; speedup vs baseline: 3.8110x; 3.8110x over previous
//
#include <hip/hip_runtime.h>

typedef unsigned int u32;
typedef _Float16 f16;
typedef __attribute__((ext_vector_type(8))) _Float16 half8;
typedef __attribute__((ext_vector_type(2))) _Float16 half2_t;
typedef __attribute__((ext_vector_type(4))) float f32x4;

#define D_IN 128
#define D_HID 128
#define D_OUT 16
#define RPB 128        // rows per bucket (lr fits in 7 bits; c < 2^20)
#define MAXBUCK 1024   // supports N <= 131072
#define CHUNK 16384    // edges per hist/scatter block (256 thr x 64)
#define PGRAN 16       // pad each row's edge run to a multiple of 16
#define SLACK 2048     // per-bucket capacity bonus; mult of 16, >= 128*15+15

// ---------------- preprocessing ----------------

// flag: 1 if edge_index is int32 layout, 0 if int64 (odd words all zero).
__global__ __launch_bounds__(256) void detect_k(const int* __restrict__ ei,
                                                u32* __restrict__ flag, int n) {
    int i = blockIdx.x * 256 + threadIdx.x;
    if (i < n && (i & 1) && ei[i] != 0) atomicOr(flag, 1u);
}

__device__ inline int load_row(const int* ei, u32 f, int e, int E) {
    return f ? ei[e] : ei[2 * e];
}
__device__ inline int load_col(const int* ei, u32 f, int e, int E) {
    return f ? ei[E + e] : ei[2 * E + 2 * e];
}
__device__ inline int clampi(int v, int n) {
    v = v < 0 ? 0 : v;
    return v >= n ? n - 1 : v;
}
__device__ inline u32 al16(u32 v) { return (v + 15u) & ~15u; }

// Pass 1: per-block histogram over row-buckets (bucket-major Hmat, plain
// stores — no global atomics at all).
__global__ __launch_bounds__(256) void hist_k(const int* __restrict__ ei,
                                              const u32* __restrict__ flag,
                                              u32* __restrict__ Hmat,
                                              int E, int N, int NBK, int NB) {
    __shared__ u32 lh[MAXBUCK];
    int tid = threadIdx.x;
    for (int i = tid; i < NBK; i += 256) lh[i] = 0;
    __syncthreads();
    u32 f = *flag;
    int base = blockIdx.x * CHUNK;
    int lim = base + CHUNK < E ? base + CHUNK : E;
    for (int e = base + tid; e < lim; e += 256) {
        int r = clampi(load_row(ei, f, e, E), N);
        atomicAdd(&lh[(u32)r >> 7], 1u);
    }
    __syncthreads();
    for (int i = tid; i < NBK; i += 256)
        Hmat[(size_t)i * NB + blockIdx.x] = lh[i];
}

__global__ __launch_bounds__(256) void scan1(const u32* __restrict__ cnt,
                                             u32* __restrict__ excl,
                                             u32* __restrict__ partial, int n) {
    __shared__ u32 sm[256];
    int tid = threadIdx.x;
    int i = blockIdx.x * 256 + tid;
    u32 v = (i < n) ? cnt[i] : 0u;
    sm[tid] = v;
    __syncthreads();
    for (int off = 1; off < 256; off <<= 1) {
        u32 t = (tid >= off) ? sm[tid - off] : 0u;
        __syncthreads();
        sm[tid] += t;
        __syncthreads();
    }
    if (i < n) excl[i] = sm[tid] - v;
    if (tid == 255) partial[blockIdx.x] = sm[255];
}

__global__ __launch_bounds__(512) void scan2(u32* __restrict__ partial, int nb) {
    __shared__ u32 sm[512];
    int tid = threadIdx.x;
    u32 v = (tid < nb) ? partial[tid] : 0u;
    sm[tid] = v;
    __syncthreads();
    for (int off = 1; off < 512; off <<= 1) {
        u32 t = (tid >= off) ? sm[tid - off] : 0u;
        __syncthreads();
        sm[tid] += t;
        __syncthreads();
    }
    if (tid < nb) partial[tid] = sm[tid] - v;
}

__global__ __launch_bounds__(256) void scan3(u32* __restrict__ excl,
                                             const u32* __restrict__ partial,
                                             int n, int E) {
    int i = blockIdx.x * 256 + threadIdx.x;
    if (i < n) excl[i] += partial[blockIdx.x];
    if (i == 0) excl[n] = (u32)E;
}

// Pass 2: re-read edges; block-exact frontiers per bucket (from scanned Hmat),
// only LDS atomics. Record = (r&127)<<20 | c (u32, c < 2^20).
__global__ __launch_bounds__(256) void scatter_bd(const int* __restrict__ ei,
                                                  const u32* __restrict__ flag,
                                                  const u32* __restrict__ Hbase,
                                                  u32* __restrict__ bdata,
                                                  int E, int N, int NBK, int NB) {
    __shared__ u32 lbase[MAXBUCK];
    int tid = threadIdx.x;
    for (int i = tid; i < NBK; i += 256)
        lbase[i] = Hbase[(size_t)i * NB + blockIdx.x];
    __syncthreads();
    u32 f = *flag;
    int base = blockIdx.x * CHUNK;
    int lim = base + CHUNK < E ? base + CHUNK : E;
    for (int e = base + tid; e < lim; e += 256) {
        int r = clampi(load_row(ei, f, e, E), N);
        int c = clampi(load_col(ei, f, e, E), N);
        u32 pos = atomicAdd(&lbase[(u32)r >> 7], 1u);
        if (pos < (u32)E) bdata[pos] = ((u32)(r & (RPB - 1)) << 20) | (u32)c;
    }
}

// Pass 3: PADDED CSR with EXPLICIT per-row ends. Each row r gets
// [row_start[r], rend[r]) with rend-beg = pdeg (mult of PGRAN, pad -> sentinel
// col N). Bucket slack is NEVER scanned (R11 bug: last row of each bucket
// inherited the slack via row_start[r+1], and those every-32nd-block
// stragglers all resonated onto one XCD -> 7.7% occupancy, 557us).
__global__ __launch_bounds__(256) void finalize_k(const u32* __restrict__ bdata,
                                                  const u32* __restrict__ Hbase,
                                                  u32* __restrict__ row_start,
                                                  u32* __restrict__ rend,
                                                  float* __restrict__ dinv,
                                                  u32* __restrict__ ecol,
                                                  int N, int E, int NB) {
    __shared__ u32 smc[RPB];
    __shared__ u32 cur[RPB];
    int b = blockIdx.x;
    int tid = threadIdx.x;
    u32 s = Hbase[(size_t)b * NB];
    u32 t = Hbase[(size_t)(b + 1) * NB];  // last bucket hits sentinel = E
    u32 pbase = al16(s) + (u32)b * SLACK;
    if (tid < RPB) smc[tid] = 0;
    __syncthreads();
    for (u32 i = s + tid; i < t; i += 256)
        atomicAdd(&smc[bdata[i] >> 20], 1u);
    __syncthreads();
    u32 deg = (tid < RPB) ? smc[tid] : 0;
    u32 pdeg = (deg + PGRAN - 1) & ~(u32)(PGRAN - 1);
    if (tid < RPB) smc[tid] = pdeg;
    __syncthreads();
    for (int off = 1; off < RPB; off <<= 1) {
        u32 tv = (tid < RPB && tid >= off) ? smc[tid - off] : 0u;
        __syncthreads();
        if (tid < RPB) smc[tid] += tv;
        __syncthreads();
    }
    u32 pexcl = (tid < RPB) ? (smc[tid] - pdeg) : 0;
    if (tid < RPB) {
        int r = b * RPB + tid;
        if (r < N) {
            row_start[r] = pbase + pexcl;
            rend[r] = pbase + pexcl + pdeg;
            dinv[r] = rsqrtf((float)(deg + 1u));  // +1 self loop
        }
        cur[tid] = pbase + pexcl;
    }
    __syncthreads();
    for (u32 i = s + tid; i < t; i += 256) {
        u32 rec = bdata[i];
        u32 pos = atomicAdd(&cur[rec >> 20], 1u);
        ecol[pos] = rec & 0xFFFFFu;
    }
    __syncthreads();
    if (tid < RPB) {  // per-row pad tail -> sentinel zero-row
        u32 st = pbase + pexcl;
        for (u32 k = deg; k < pdeg; k++) ecol[st + k] = (u32)N;
    }
    // bucket slack never read (rend bounds every row) -> no fill needed.
}

// Split fp32 W into hi/lo f16 MFMA B-fragments. Blocks 0-7 -> W1, 8-15 -> W2,
// 16 -> W3, 17 -> zero the sentinel rows h[N], h3[N].
__global__ __launch_bounds__(256) void reformat_all(const float* __restrict__ W1,
                                                    const float* __restrict__ W2,
                                                    const float* __restrict__ W3,
                                                    f16* __restrict__ W1h, f16* __restrict__ W1l,
                                                    f16* __restrict__ W2h, f16* __restrict__ W2l,
                                                    f16* __restrict__ W3h, f16* __restrict__ W3l,
                                                    f16* __restrict__ hzero,
                                                    f16* __restrict__ h3zero) {
    if (blockIdx.x == 17) {
        int tix = threadIdx.x;
        if (tix < 128) hzero[tix] = (f16)0;
        else if (tix < 144) h3zero[tix - 128] = (f16)0;
        return;
    }
    const float* W;
    f16 *Wh, *Wl;
    int ntiles, bidx;
    if (blockIdx.x < 8) { W = W1; Wh = W1h; Wl = W1l; ntiles = 8; bidx = blockIdx.x; }
    else if (blockIdx.x < 16) { W = W2; Wh = W2h; Wl = W2l; ntiles = 8; bidx = blockIdx.x - 8; }
    else { W = W3; Wh = W3h; Wl = W3l; ntiles = 1; bidx = 0; }
    int idx = bidx * 256 + threadIdx.x;
    int total = 4 * ntiles * 64;
    if (idx >= total) return;
    int lane = idx & 63;
    int st = idx >> 6;
    int t = st % ntiles;
    int s = st / ntiles;
    int Nc = ntiles * 16;
    int n = t * 16 + (lane & 15);
    int kb = lane >> 4;
    half8 vh, vl;
#pragma unroll
    for (int j = 0; j < 8; j++) {
        float w = W[(size_t)(s * 32 + kb * 8 + j) * Nc + n];
        f16 hi = (f16)w;
        f16 lo = (f16)(w - (float)hi);
        vh[j] = hi;
        vl[j] = lo;
    }
    *(half8*)(Wh + (size_t)idx * 8) = vh;
    *(half8*)(Wl + (size_t)idx * 8) = vl;
}

// ---------------- GEMMs (f16 MFMA 16x16x32, fp32-accurate via splits) --------

// Layer 1: A fp32 [M x 128]; 3 MFMAs; epilogue scales row rr by dinv[rr]
// so the stored table is h' = (x@W1)*dinv  (norm folded into storage).
__global__ __launch_bounds__(256) void gemm128_l1(const float* __restrict__ A,
                                                  const f16* __restrict__ Wh,
                                                  const f16* __restrict__ Wl,
                                                  const float* __restrict__ dinv,
                                                  f16* __restrict__ H, int M) {
    int wave = threadIdx.x >> 6, lane = threadIdx.x & 63;
    int mbase = blockIdx.x * 64 + wave * 16;
    int mload = mbase + (lane & 15);
    if (mload >= M) mload = M - 1;
    int kq = lane >> 4;
    f32x4 acc[8];
#pragma unroll
    for (int t = 0; t < 8; t++) acc[t] = (f32x4){0.f, 0.f, 0.f, 0.f};
#pragma unroll
    for (int s = 0; s < 4; s++) {
        const float* ap = A + (size_t)mload * 128 + s * 32 + kq * 8;
        half8 ah, al;
#pragma unroll
        for (int j = 0; j < 8; j++) {
            float v = ap[j];
            f16 hi = (f16)v;
            ah[j] = hi;
            al[j] = (f16)(v - (float)hi);
        }
#pragma unroll
        for (int t = 0; t < 8; t++) {
            half8 bh = *(const half8*)(Wh + (size_t)((s * 8 + t) * 64 + lane) * 8);
            half8 bl = *(const half8*)(Wl + (size_t)((s * 8 + t) * 64 + lane) * 8);
            acc[t] = __builtin_amdgcn_mfma_f32_16x16x32_f16(ah, bh, acc[t], 0, 0, 0);
            acc[t] = __builtin_amdgcn_mfma_f32_16x16x32_f16(ah, bl, acc[t], 0, 0, 0);
            acc[t] = __builtin_amdgcn_mfma_f32_16x16x32_f16(al, bh, acc[t], 0, 0, 0);
        }
    }
    int coln = lane & 15;
    int rbase = mbase + ((lane >> 4) << 2);
    float dsc[4];
#pragma unroll
    for (int i = 0; i < 4; i++) {
        int rr = rbase + i;
        dsc[i] = dinv[rr < M ? rr : M - 1];
    }
#pragma unroll
    for (int t = 0; t < 8; t++) {
#pragma unroll
        for (int i = 0; i < 4; i++) {
            int rr = rbase + i;
            if (rr < M) H[(size_t)rr * 128 + t * 16 + coln] = (f16)(acc[t][i] * dsc[i]);
        }
    }
}

// Layer 2: A f16 (pre-scaled act') [M x 128]; 2 MFMAs; output inherits the
// dinv row-scale automatically ((act*dinv)@W = (act@W)*dinv).
__global__ __launch_bounds__(256) void gemm128_l2(const f16* __restrict__ A,
                                                  const f16* __restrict__ Wh,
                                                  const f16* __restrict__ Wl,
                                                  f16* __restrict__ H, int M) {
    int wave = threadIdx.x >> 6, lane = threadIdx.x & 63;
    int mbase = blockIdx.x * 64 + wave * 16;
    int mload = mbase + (lane & 15);
    if (mload >= M) mload = M - 1;
    int kq = lane >> 4;
    f32x4 acc[8];
#pragma unroll
    for (int t = 0; t < 8; t++) acc[t] = (f32x4){0.f, 0.f, 0.f, 0.f};
#pragma unroll
    for (int s = 0; s < 4; s++) {
        half8 a = *(const half8*)(A + (size_t)mload * 128 + s * 32 + kq * 8);
#pragma unroll
        for (int t = 0; t < 8; t++) {
            half8 bh = *(const half8*)(Wh + (size_t)((s * 8 + t) * 64 + lane) * 8);
            half8 bl = *(const half8*)(Wl + (size_t)((s * 8 + t) * 64 + lane) * 8);
            acc[t] = __builtin_amdgcn_mfma_f32_16x16x32_f16(a, bh, acc[t], 0, 0, 0);
            acc[t] = __builtin_amdgcn_mfma_f32_16x16x32_f16(a, bl, acc[t], 0, 0, 0);
        }
    }
    int coln = lane & 15;
    int rbase = mbase + ((lane >> 4) << 2);
#pragma unroll
    for (int t = 0; t < 8; t++) {
#pragma unroll
        for (int i = 0; i < 4; i++) {
            int rr = rbase + i;
            if (rr < M) H[(size_t)rr * 128 + t * 16 + coln] = (f16)acc[t][i];
        }
    }
}

// Layer 3: A f16 (pre-scaled) [M x 128] -> H3' f16 [M x 16].
__global__ __launch_bounds__(256) void gemm16(const f16* __restrict__ A,
                                              const f16* __restrict__ Wh,
                                              const f16* __restrict__ Wl,
                                              f16* __restrict__ H, int M) {
    int wave = threadIdx.x >> 6, lane = threadIdx.x & 63;
    int mbase = blockIdx.x * 64 + wave * 16;
    int mload = mbase + (lane & 15);
    if (mload >= M) mload = M - 1;
    int kq = lane >> 4;
    f32x4 acc = (f32x4){0.f, 0.f, 0.f, 0.f};
#pragma unroll
    for (int s = 0; s < 4; s++) {
        half8 a = *(const half8*)(A + (size_t)mload * 128 + s * 32 + kq * 8);
        half8 bh = *(const half8*)(Wh + (size_t)(s * 64 + lane) * 8);
        half8 bl = *(const half8*)(Wl + (size_t)(s * 64 + lane) * 8);
        acc = __builtin_amdgcn_mfma_f32_16x16x32_f16(a, bh, acc, 0, 0, 0);
        acc = __builtin_amdgcn_mfma_f32_16x16x32_f16(a, bl, acc, 0, 0, 0);
    }
    int coln = lane & 15;
    int rbase = mbase + ((lane >> 4) << 2);
#pragma unroll
    for (int i = 0; i < 4; i++) {
        int rr = rbase + i;
        if (rr < M) H[(size_t)rr * 16 + coln] = (f16)acc[i];
    }
}

// ---------------- aggregation ----------------
// One wave per row; lane handles features 2*lane, 2*lane+1 (half2, 4B/lane ->
// one coalesced 256B gather per edge). Padded CSR with explicit rend: every
// range is exactly pdeg (mult of 16) entries -> single full-width batch loop,
// no tails, no slack scans. f32 accumulation (R8 numerics).
__global__ __launch_bounds__(256) void agg128(const f16* __restrict__ h,
                                              const u32* __restrict__ ecol,
                                              const u32* __restrict__ row_start,
                                              const u32* __restrict__ rend,
                                              const float* __restrict__ dinv,
                                              const float* __restrict__ bias,
                                              f16* __restrict__ out, int M) {
    int wave = threadIdx.x >> 6, lane = threadIdx.x & 63;
    int r = blockIdx.x * 4 + wave;
    if (r >= M) return;
    u32 beg = row_start[r], end = rend[r];
    const half2_t* hp = (const half2_t*)h;
    float ax0 = 0, ay0 = 0, ax1 = 0, ay1 = 0, ax2 = 0, ay2 = 0, ax3 = 0, ay3 = 0;
    for (u32 e = beg; e < end; e += 16) {
        u32 c[16];
#pragma unroll
        for (int j = 0; j < 16; j++) c[j] = ecol[e + j];
        half2_t v[16];
#pragma unroll
        for (int j = 0; j < 16; j++) v[j] = hp[(size_t)c[j] * 64 + lane];
#pragma unroll
        for (int j = 0; j < 16; j += 4) {
            ax0 += (float)v[j][0];     ay0 += (float)v[j][1];
            ax1 += (float)v[j + 1][0]; ay1 += (float)v[j + 1][1];
            ax2 += (float)v[j + 2][0]; ay2 += (float)v[j + 2][1];
            ax3 += (float)v[j + 3][0]; ay3 += (float)v[j + 3][1];
        }
    }
    half2_t vs = hp[(size_t)r * 64 + lane];
    float dr = dinv[r];
    float2 bb = ((const float2*)bias)[lane];
    float ax = (((ax0 + ax1) + (ax2 + ax3)) + (float)vs[0]) * dr + bb.x;
    float ay = (((ay0 + ay1) + (ay2 + ay3)) + (float)vs[1]) * dr + bb.y;
    ax = fmaxf(ax, 0.f) * dr;  // pre-scale for next layer's gather
    ay = fmaxf(ay, 0.f) * dr;
    half2_t o;
    o[0] = (f16)ax;
    o[1] = (f16)ay;
    ((half2_t*)out)[(size_t)r * 64 + lane] = o;
}

// 16 lanes per row; h3' pre-scaled; padded CSR -> pure 8-batches, no tail.
__global__ __launch_bounds__(256) void agg16_lsm(const f16* __restrict__ h3,
                                                 const u32* __restrict__ ecol,
                                                 const u32* __restrict__ row_start,
                                                 const u32* __restrict__ rend,
                                                 const float* __restrict__ dinv,
                                                 const float* __restrict__ bias,
                                                 float* __restrict__ out, int M) {
    int g = threadIdx.x >> 4, l = threadIdx.x & 15;
    int r = blockIdx.x * 16 + g;
    if (r >= M) return;
    u32 beg = row_start[r], end = rend[r];
    float a0 = 0.f, a1 = 0.f, a2 = 0.f, a3 = 0.f;
    for (u32 e = beg; e < end; e += 8) {
        u32 c[8];
#pragma unroll
        for (int j = 0; j < 8; j++) c[j] = ecol[e + j];
        f16 v[8];
#pragma unroll
        for (int j = 0; j < 8; j++) v[j] = h3[(size_t)c[j] * 16 + l];
        a0 += (float)v[0] + (float)v[4];
        a1 += (float)v[1] + (float)v[5];
        a2 += (float)v[2] + (float)v[6];
        a3 += (float)v[3] + (float)v[7];
    }
    float dr = dinv[r];
    float acc = (((a0 + a1) + (a2 + a3)) + (float)h3[(size_t)r * 16 + l]) * dr +
                bias[l];
    float m = acc;
#pragma unroll
    for (int o = 8; o >= 1; o >>= 1) m = fmaxf(m, __shfl_xor(m, o, 16));
    float ex = expf(acc - m);
    float s = ex;
#pragma unroll
    for (int o = 8; o >= 1; o >>= 1) s += __shfl_xor(s, o, 16);
    out[(size_t)r * 16 + l] = acc - m - logf(s);
}

// ---------------- launch ----------------

extern "C" void kernel_launch(void* const* d_in, const int* in_sizes, int n_in,
                              void* d_out, int out_size, void* d_ws, size_t ws_size,
                              hipStream_t stream) {
    const float* x = (const float*)d_in[0];
    const int* ei = (const int*)d_in[1];
    const float* W1 = (const float*)d_in[2];
    const float* b1 = (const float*)d_in[3];
    const float* W2 = (const float*)d_in[4];
    const float* b2 = (const float*)d_in[5];
    const float* W3 = (const float*)d_in[6];
    const float* b3 = (const float*)d_in[7];
    int N = in_sizes[0] / D_IN;
    int E = in_sizes[1] / 2;

    int NBK = (N + RPB - 1) / RPB;     // 782 row-buckets (<= MAXBUCK)
    int NB = (E + CHUNK - 1) / CHUNK;  // 98 hist/scatter blocks
    int L = NBK * NB;                  // 76636 Hmat entries
    size_t Epad = ((size_t)E + 16) + (size_t)NBK * SLACK + 256;

    char* p = (char*)d_ws;
    auto alloc = [&](size_t bytes) -> void* {
        void* q = (void*)p;
        p += (bytes + 255) & ~(size_t)255;
        return q;
    };
    u32* flag = (u32*)alloc(256);
    float* dinv = (float*)alloc((size_t)N * 4);
    u32* row_start = (u32*)alloc((size_t)(N + 1) * 4);
    u32* rend = (u32*)alloc((size_t)N * 4);
    u32* partial2 = (u32*)alloc(4096);
    u32* Hmat = (u32*)alloc((size_t)(L + 1) * 4);
    u32* ecol = (u32*)alloc(Epad * 4);
    u32* bdata = (u32*)alloc((size_t)E * 4);
    f16* wf1h = (f16*)alloc(16384 * 2);
    f16* wf1l = (f16*)alloc(16384 * 2);
    f16* wf2h = (f16*)alloc(16384 * 2);
    f16* wf2l = (f16*)alloc(16384 * 2);
    f16* wf3h = (f16*)alloc(2048 * 2);
    f16* wf3l = (f16*)alloc(2048 * 2);
    f16* h = (f16*)alloc((size_t)(N + 1) * 128 * 2);   // +1 sentinel zero row
    f16* act = (f16*)alloc((size_t)N * 128 * 2);
    f16* h3 = (f16*)alloc((size_t)(N + 1) * 16 * 2);   // +1 sentinel zero row
    (void)ws_size; (void)n_in; (void)out_size;

    hipMemsetAsync(flag, 0, 4, stream);

    int nb2 = (L + 255) / 256;  // 300 <= 512 for scan2

    detect_k<<<32, 256, 0, stream>>>(ei, flag, 8192);
    hist_k<<<NB, 256, 0, stream>>>(ei, flag, Hmat, E, N, NBK, NB);
    scan1<<<nb2, 256, 0, stream>>>(Hmat, Hmat, partial2, L);
    scan2<<<1, 512, 0, stream>>>(partial2, nb2);
    scan3<<<nb2, 256, 0, stream>>>(Hmat, partial2, L, E);  // sentinel Hmat[L]=E
    scatter_bd<<<NB, 256, 0, stream>>>(ei, flag, Hmat, bdata, E, N, NBK, NB);
    finalize_k<<<NBK, 256, 0, stream>>>(bdata, Hmat, row_start, rend, dinv,
                                        ecol, N, E, NB);

    reformat_all<<<18, 256, 0, stream>>>(W1, W2, W3, wf1h, wf1l, wf2h, wf2l,
                                         wf3h, wf3l,
                                         h + (size_t)N * 128,
                                         h3 + (size_t)N * 16);

    int gb = (N + 63) / 64;
    int ab = (N + 3) / 4;
    gemm128_l1<<<gb, 256, 0, stream>>>(x, wf1h, wf1l, dinv, h, N);
    agg128<<<ab, 256, 0, stream>>>(h, ecol, row_start, rend, dinv, b1, act, N);
    gemm128_l2<<<gb, 256, 0, stream>>>(act, wf2h, wf2l, h, N);
    agg128<<<ab, 256, 0, stream>>>(h, ecol, row_start, rend, dinv, b2, act, N);
    gemm16<<<gb, 256, 0, stream>>>(act, wf3h, wf3l, h3, N);
    agg16_lsm<<<(N + 15) / 16, 256, 0, stream>>>(h3, ecol, row_start, rend,
                                                 dinv, b3, (float*)d_out, N);
}